// Round 1
// baseline (2078.008 us; speedup 1.0000x reference)
//
#include <hip/hip_runtime.h>
#include <cstddef>

#define B_ 512
#define T_ 2048
#define I_ 16
#define H_ 40

// tanh(x) = 1 - 2/(exp(2x)+1); exp(2x) = exp2(x * 2*log2(e))
// v_exp_f32 / v_rcp_f32 are ~1 ulp -> abs error ~2e-7; saturates correctly to +/-1.
__device__ __forceinline__ float fast_tanh(float x) {
  float e = __builtin_amdgcn_exp2f(x * 2.8853900817779268f);
  return 1.0f - 2.0f * __builtin_amdgcn_rcpf(e + 1.0f);
}

__global__ __launch_bounds__(64, 1)
void rnn3_fused(const float* __restrict__ x,
                const float* __restrict__ wih0, const float* __restrict__ whh0,
                const float* __restrict__ bih0, const float* __restrict__ bhh0,
                const float* __restrict__ wih1, const float* __restrict__ whh1,
                const float* __restrict__ bih1, const float* __restrict__ bhh1,
                const float* __restrict__ wih2, const float* __restrict__ whh2,
                const float* __restrict__ bih2, const float* __restrict__ bhh2,
                const float* __restrict__ fcw, const float* __restrict__ fcb,
                float* __restrict__ out) {
  const int b = blockIdx.x;
  const int j = threadIdx.x;            // lane = hidden unit (j < 40 real)
  const int jr = (j < H_) ? j : (H_ - 1); // clamp so lanes 40..63 load finite junk

  // ---- all weights resident in VGPRs (216 regs/lane) ----
  float w0i[I_], w0h[H_], w1i[H_], w1h[H_], w2i[H_], w2h[H_];
#pragma unroll
  for (int k = 0; k < I_; ++k) w0i[k] = wih0[jr * I_ + k];
#pragma unroll
  for (int k = 0; k < H_; ++k) w0h[k] = whh0[jr * H_ + k];
#pragma unroll
  for (int k = 0; k < H_; ++k) w1i[k] = wih1[jr * H_ + k];
#pragma unroll
  for (int k = 0; k < H_; ++k) w1h[k] = whh1[jr * H_ + k];
#pragma unroll
  for (int k = 0; k < H_; ++k) w2i[k] = wih2[jr * H_ + k];
#pragma unroll
  for (int k = 0; k < H_; ++k) w2h[k] = whh2[jr * H_ + k];

  const float bias0 = bih0[jr] + bhh0[jr];
  const float bias1 = bih1[jr] + bhh1[jr];
  const float bias2 = bih2[jr] + bhh2[jr];

  // h broadcast buffer (uniform ds_read_b128 = LDS broadcast, conflict-free)
  __shared__ float hb[3][64];
  hb[0][j] = 0.f; hb[1][j] = 0.f; hb[2][j] = 0.f;
  __syncthreads();

  const float* __restrict__ xb = x + (size_t)b * (T_ * I_);

  // x is wave-uniform -> scalar loads; double-prefetch (2 steps ahead) to hide HBM latency
  float xc[I_], xn[I_];
#pragma unroll
  for (int k = 0; k < I_; ++k) xc[k] = xb[k];        // t = 0
#pragma unroll
  for (int k = 0; k < I_; ++k) xn[k] = xb[I_ + k];   // t = 1

  float nh2 = 0.f;

  for (int t = 0; t < T_; ++t) {
    // prefetch x(t+2) (clamped address, always issued -> branch-free)
    const int tf = (t + 2 < T_) ? (t + 2) : (T_ - 1);
    const float* __restrict__ xf = xb + (size_t)tf * I_;
    float xp[I_];
#pragma unroll
    for (int k = 0; k < I_; ++k) xp[k] = xf[k];

    // ---------------- layer 0 ----------------
    float a0 = 0.f, a1 = 0.f, a2 = 0.f, a3 = 0.f;
#pragma unroll
    for (int kk = 0; kk < I_ / 4; ++kk) {
      a0 += xc[4 * kk + 0] * w0i[4 * kk + 0];
      a1 += xc[4 * kk + 1] * w0i[4 * kk + 1];
      a2 += xc[4 * kk + 2] * w0i[4 * kk + 2];
      a3 += xc[4 * kk + 3] * w0i[4 * kk + 3];
    }
    float r0 = 0.f, r1 = 0.f, r2 = 0.f, r3 = 0.f;
#pragma unroll
    for (int kk = 0; kk < H_ / 4; ++kk) {
      const float4 hv = *(const float4*)(&hb[0][4 * kk]);   // old h0 (broadcast)
      r0 += hv.x * w0h[4 * kk + 0];
      r1 += hv.y * w0h[4 * kk + 1];
      r2 += hv.z * w0h[4 * kk + 2];
      r3 += hv.w * w0h[4 * kk + 3];
    }
    const float nh0 = fast_tanh(bias0 + ((a0 + a1) + (a2 + a3)) + ((r0 + r1) + (r2 + r3)));
    hb[0][j] = nh0;   // same-wave DS ops are in-order: later reads see new h0

    // ---------------- layer 1 ----------------
    a0 = a1 = a2 = a3 = 0.f;
#pragma unroll
    for (int kk = 0; kk < H_ / 4; ++kk) {
      const float4 hv = *(const float4*)(&hb[0][4 * kk]);   // NEW h0
      a0 += hv.x * w1i[4 * kk + 0];
      a1 += hv.y * w1i[4 * kk + 1];
      a2 += hv.z * w1i[4 * kk + 2];
      a3 += hv.w * w1i[4 * kk + 3];
    }
    r0 = r1 = r2 = r3 = 0.f;
#pragma unroll
    for (int kk = 0; kk < H_ / 4; ++kk) {
      const float4 hv = *(const float4*)(&hb[1][4 * kk]);   // old h1
      r0 += hv.x * w1h[4 * kk + 0];
      r1 += hv.y * w1h[4 * kk + 1];
      r2 += hv.z * w1h[4 * kk + 2];
      r3 += hv.w * w1h[4 * kk + 3];
    }
    const float nh1 = fast_tanh(bias1 + ((a0 + a1) + (a2 + a3)) + ((r0 + r1) + (r2 + r3)));
    hb[1][j] = nh1;

    // ---------------- layer 2 ----------------
    a0 = a1 = a2 = a3 = 0.f;
#pragma unroll
    for (int kk = 0; kk < H_ / 4; ++kk) {
      const float4 hv = *(const float4*)(&hb[1][4 * kk]);   // NEW h1
      a0 += hv.x * w2i[4 * kk + 0];
      a1 += hv.y * w2i[4 * kk + 1];
      a2 += hv.z * w2i[4 * kk + 2];
      a3 += hv.w * w2i[4 * kk + 3];
    }
    r0 = r1 = r2 = r3 = 0.f;
#pragma unroll
    for (int kk = 0; kk < H_ / 4; ++kk) {
      const float4 hv = *(const float4*)(&hb[2][4 * kk]);   // old h2
      r0 += hv.x * w2h[4 * kk + 0];
      r1 += hv.y * w2h[4 * kk + 1];
      r2 += hv.z * w2h[4 * kk + 2];
      r3 += hv.w * w2h[4 * kk + 3];
    }
    nh2 = fast_tanh(bias2 + ((a0 + a1) + (a2 + a3)) + ((r0 + r1) + (r2 + r3)));
    hb[2][j] = nh2;

    // rotate x prefetch buffers
#pragma unroll
    for (int k = 0; k < I_; ++k) { xc[k] = xn[k]; xn[k] = xp[k]; }
  }

  // ---------------- FC head: out[b] = sum_j fc_w[j]*h2[j] + fc_b ----------------
  const float fw = (j < H_) ? fcw[j] : 0.f;
  float v = nh2 * fw;   // lanes >= 40 contribute 0 (finite garbage * 0)
#pragma unroll
  for (int off = 32; off > 0; off >>= 1) v += __shfl_down(v, off);
  if (j == 0) out[b] = v + fcb[0];
}

extern "C" void kernel_launch(void* const* d_in, const int* in_sizes, int n_in,
                              void* d_out, int out_size, void* d_ws, size_t ws_size,
                              hipStream_t stream) {
  (void)in_sizes; (void)n_in; (void)d_ws; (void)ws_size; (void)out_size;
  const float* x    = (const float*)d_in[0];
  const float* wih0 = (const float*)d_in[1];
  const float* whh0 = (const float*)d_in[2];
  const float* bih0 = (const float*)d_in[3];
  const float* bhh0 = (const float*)d_in[4];
  const float* wih1 = (const float*)d_in[5];
  const float* whh1 = (const float*)d_in[6];
  const float* bih1 = (const float*)d_in[7];
  const float* bhh1 = (const float*)d_in[8];
  const float* wih2 = (const float*)d_in[9];
  const float* whh2 = (const float*)d_in[10];
  const float* bih2 = (const float*)d_in[11];
  const float* bhh2 = (const float*)d_in[12];
  const float* fcw  = (const float*)d_in[13];
  const float* fcb  = (const float*)d_in[14];
  float* out = (float*)d_out;

  hipLaunchKernelGGL(rnn3_fused, dim3(B_), dim3(64), 0, stream,
                     x, wih0, whh0, bih0, bhh0,
                     wih1, whh1, bih1, bhh1,
                     wih2, whh2, bih2, bhh2,
                     fcw, fcb, out);
}

// Round 2
// 2072.473 us; speedup vs baseline: 1.0027x; 1.0027x over previous
//
#include <hip/hip_runtime.h>
#include <cstddef>

#define B_ 512
#define T_ 2048
#define I_ 16
#define H_ 40

// tanh(x) = 1 - 2/(exp(2x)+1); exp(2x) = exp2(x * 2*log2(e))
// v_exp_f32 / v_rcp_f32 are ~1 ulp -> abs error ~2e-7; saturates correctly to +/-1.
__device__ __forceinline__ float fast_tanh(float x) {
  float e = __builtin_amdgcn_exp2f(x * 2.8853900817779268f);
  return 1.0f - 2.0f * __builtin_amdgcn_rcpf(e + 1.0f);
}

// Force a loaded value to stay resident in a VGPR: the asm "writes" it, so the
// compiler cannot rematerialize the load inside the t-loop (round-1 failure:
// VGPR_Count=128 < 216 resident weights -> per-step L1/L2 weight reloads).
#define PIN(v) asm volatile("" : "+v"(v))

__global__ __launch_bounds__(64, 1)
void rnn3_fused(const float* __restrict__ x,
                const float* __restrict__ wih0, const float* __restrict__ whh0,
                const float* __restrict__ bih0, const float* __restrict__ bhh0,
                const float* __restrict__ wih1, const float* __restrict__ whh1,
                const float* __restrict__ bih1, const float* __restrict__ bhh1,
                const float* __restrict__ wih2, const float* __restrict__ whh2,
                const float* __restrict__ bih2, const float* __restrict__ bhh2,
                const float* __restrict__ fcw, const float* __restrict__ fcb,
                float* __restrict__ out) {
  const int b = blockIdx.x;
  const int j = threadIdx.x;              // lane = hidden unit (j < 40 real)
  const int jr = (j < H_) ? j : (H_ - 1); // clamp so lanes 40..63 load finite junk

  // ---- all weights resident in VGPRs (216 regs/lane), pinned ----
  float w0i[I_], w0h[H_], w1i[H_], w1h[H_], w2i[H_], w2h[H_];
#pragma unroll
  for (int k = 0; k < I_; ++k) { w0i[k] = wih0[jr * I_ + k]; PIN(w0i[k]); }
#pragma unroll
  for (int k = 0; k < H_; ++k) { w0h[k] = whh0[jr * H_ + k]; PIN(w0h[k]); }
#pragma unroll
  for (int k = 0; k < H_; ++k) { w1i[k] = wih1[jr * H_ + k]; PIN(w1i[k]); }
#pragma unroll
  for (int k = 0; k < H_; ++k) { w1h[k] = whh1[jr * H_ + k]; PIN(w1h[k]); }
#pragma unroll
  for (int k = 0; k < H_; ++k) { w2i[k] = wih2[jr * H_ + k]; PIN(w2i[k]); }
#pragma unroll
  for (int k = 0; k < H_; ++k) { w2h[k] = whh2[jr * H_ + k]; PIN(w2h[k]); }

  float bias0 = bih0[jr] + bhh0[jr]; PIN(bias0);
  float bias1 = bih1[jr] + bhh1[jr]; PIN(bias1);
  float bias2 = bih2[jr] + bhh2[jr]; PIN(bias2);

  // h broadcast buffer (uniform ds_read_b128 = LDS broadcast, conflict-free)
  __shared__ float hb[3][64];
  hb[0][j] = 0.f; hb[1][j] = 0.f; hb[2][j] = 0.f;
  __syncthreads();

  const float* __restrict__ xb = x + (size_t)b * (T_ * I_);

  // x is wave-uniform -> scalar loads; double-prefetch (2 steps ahead) to hide HBM latency
  float xc[I_], xn[I_];
#pragma unroll
  for (int k = 0; k < I_; ++k) xc[k] = xb[k];        // t = 0
#pragma unroll
  for (int k = 0; k < I_; ++k) xn[k] = xb[I_ + k];   // t = 1

  float nh2 = 0.f;

  for (int t = 0; t < T_; ++t) {
    // prefetch x(t+2) (clamped address, always issued -> branch-free)
    const int tf = (t + 2 < T_) ? (t + 2) : (T_ - 1);
    const float* __restrict__ xf = xb + (size_t)tf * I_;
    float xp[I_];
#pragma unroll
    for (int k = 0; k < I_; ++k) xp[k] = xf[k];

    // ---------------- layer 0 ----------------
    float a0 = bias0, a1 = 0.f, a2 = 0.f, a3 = 0.f;
#pragma unroll
    for (int kk = 0; kk < I_ / 4; ++kk) {
      a0 += xc[4 * kk + 0] * w0i[4 * kk + 0];
      a1 += xc[4 * kk + 1] * w0i[4 * kk + 1];
      a2 += xc[4 * kk + 2] * w0i[4 * kk + 2];
      a3 += xc[4 * kk + 3] * w0i[4 * kk + 3];
    }
    float r0 = 0.f, r1 = 0.f, r2 = 0.f, r3 = 0.f;
#pragma unroll
    for (int kk = 0; kk < H_ / 4; ++kk) {
      const float4 hv = *(const float4*)(&hb[0][4 * kk]);   // old h0 (broadcast)
      r0 += hv.x * w0h[4 * kk + 0];
      r1 += hv.y * w0h[4 * kk + 1];
      r2 += hv.z * w0h[4 * kk + 2];
      r3 += hv.w * w0h[4 * kk + 3];
    }
    const float nh0 = fast_tanh(((a0 + a1) + (a2 + a3)) + ((r0 + r1) + (r2 + r3)));
    hb[0][j] = nh0;   // same-wave DS ops are in-order: later reads see new h0

    // ---------------- layer 1 ----------------
    a0 = bias1; a1 = a2 = a3 = 0.f;
#pragma unroll
    for (int kk = 0; kk < H_ / 4; ++kk) {
      const float4 hv = *(const float4*)(&hb[0][4 * kk]);   // NEW h0
      a0 += hv.x * w1i[4 * kk + 0];
      a1 += hv.y * w1i[4 * kk + 1];
      a2 += hv.z * w1i[4 * kk + 2];
      a3 += hv.w * w1i[4 * kk + 3];
    }
    r0 = r1 = r2 = r3 = 0.f;
#pragma unroll
    for (int kk = 0; kk < H_ / 4; ++kk) {
      const float4 hv = *(const float4*)(&hb[1][4 * kk]);   // old h1
      r0 += hv.x * w1h[4 * kk + 0];
      r1 += hv.y * w1h[4 * kk + 1];
      r2 += hv.z * w1h[4 * kk + 2];
      r3 += hv.w * w1h[4 * kk + 3];
    }
    const float nh1 = fast_tanh(((a0 + a1) + (a2 + a3)) + ((r0 + r1) + (r2 + r3)));
    hb[1][j] = nh1;

    // ---------------- layer 2 ----------------
    a0 = bias2; a1 = a2 = a3 = 0.f;
#pragma unroll
    for (int kk = 0; kk < H_ / 4; ++kk) {
      const float4 hv = *(const float4*)(&hb[1][4 * kk]);   // NEW h1
      a0 += hv.x * w2i[4 * kk + 0];
      a1 += hv.y * w2i[4 * kk + 1];
      a2 += hv.z * w2i[4 * kk + 2];
      a3 += hv.w * w2i[4 * kk + 3];
    }
    r0 = r1 = r2 = r3 = 0.f;
#pragma unroll
    for (int kk = 0; kk < H_ / 4; ++kk) {
      const float4 hv = *(const float4*)(&hb[2][4 * kk]);   // old h2
      r0 += hv.x * w2h[4 * kk + 0];
      r1 += hv.y * w2h[4 * kk + 1];
      r2 += hv.z * w2h[4 * kk + 2];
      r3 += hv.w * w2h[4 * kk + 3];
    }
    nh2 = fast_tanh(((a0 + a1) + (a2 + a3)) + ((r0 + r1) + (r2 + r3)));
    hb[2][j] = nh2;

    // rotate x prefetch buffers
#pragma unroll
    for (int k = 0; k < I_; ++k) { xc[k] = xn[k]; xn[k] = xp[k]; }
  }

  // ---------------- FC head: out[b] = sum_j fc_w[j]*h2[j] + fc_b ----------------
  const float fw = (j < H_) ? fcw[j] : 0.f;
  float v = nh2 * fw;   // lanes >= 40 contribute 0 (finite garbage * 0)
#pragma unroll
  for (int off = 32; off > 0; off >>= 1) v += __shfl_down(v, off);
  if (j == 0) out[b] = v + fcb[0];
}

extern "C" void kernel_launch(void* const* d_in, const int* in_sizes, int n_in,
                              void* d_out, int out_size, void* d_ws, size_t ws_size,
                              hipStream_t stream) {
  (void)in_sizes; (void)n_in; (void)d_ws; (void)ws_size; (void)out_size;
  const float* x    = (const float*)d_in[0];
  const float* wih0 = (const float*)d_in[1];
  const float* whh0 = (const float*)d_in[2];
  const float* bih0 = (const float*)d_in[3];
  const float* bhh0 = (const float*)d_in[4];
  const float* wih1 = (const float*)d_in[5];
  const float* whh1 = (const float*)d_in[6];
  const float* bih1 = (const float*)d_in[7];
  const float* bhh1 = (const float*)d_in[8];
  const float* wih2 = (const float*)d_in[9];
  const float* whh2 = (const float*)d_in[10];
  const float* bih2 = (const float*)d_in[11];
  const float* bhh2 = (const float*)d_in[12];
  const float* fcw  = (const float*)d_in[13];
  const float* fcb  = (const float*)d_in[14];
  float* out = (float*)d_out;

  hipLaunchKernelGGL(rnn3_fused, dim3(B_), dim3(64), 0, stream,
                     x, wih0, whh0, bih0, bhh0,
                     wih1, whh1, bih1, bhh1,
                     wih2, whh2, bih2, bhh2,
                     fcw, fcb, out);
}

// Round 4
// 1102.115 us; speedup vs baseline: 1.8855x; 1.8805x over previous
//
#include <hip/hip_runtime.h>
#include <cstddef>
#include <cstdint>

#define B_ 512
#define T_ 2048
#define I_ 16
#define H_ 40

typedef __fp16 half_t;  // matches __builtin_amdgcn_* vector element type exactly
typedef half_t h2 __attribute__((ext_vector_type(2)));
typedef half_t h8 __attribute__((ext_vector_type(8)));

// tanh(x) = 1 - 2/(exp(2x)+1); exp(2x) = exp2(x * 2*log2(e)).
__device__ __forceinline__ float fast_tanh(float x) {
  float e = __builtin_amdgcn_exp2f(x * 2.8853900817779268f);
  return 1.0f - 2.0f * __builtin_amdgcn_rcpf(e + 1.0f);
}

// v_dot2_f32_f16: 2 fp16 MACs with f32 accumulate in one VALU op.
__device__ __forceinline__ float dot2(h2 a, h2 b, float c) {
#if __has_builtin(__builtin_amdgcn_fdot2)
  return __builtin_amdgcn_fdot2(a, b, c, false);
#else
  return c + (float)a[0] * (float)b[0] + (float)a[1] * (float)b[1];
#endif
}

__device__ __forceinline__ h2 pack2(float lo, float hi) {
#if __has_builtin(__builtin_amdgcn_cvt_pkrtz)
  return __builtin_amdgcn_cvt_pkrtz(lo, hi);
#else
  h2 r; r[0] = (half_t)lo; r[1] = (half_t)hi; return r;
#endif
}

#define PIN(v) asm volatile("" : "+v"(v))

// Pack one f32 weight row (stride STR, N2 half2 pairs) into resident half2 VGPRs.
#define LOADW(DST, SRC, STR, N2)                                    \
  _Pragma("unroll") for (int k = 0; k < (N2); ++k) {                \
    DST[k][0] = (half_t)SRC[jr * (STR) + 2 * k];                    \
    DST[k][1] = (half_t)SRC[jr * (STR) + 2 * k + 1];                \
    PIN(DST[k]);                                                    \
  }

// 40-wide dot against LDS-broadcast h (fp16): 5 uniform 16B reads, 20 dot2.
// h2 extracts are register-pair aligned -> zero shuffle cost.
#define HD(HP, W)                                                   \
  do {                                                              \
    _Pragma("unroll") for (int m = 0; m < 5; ++m) {                 \
      h8 q = (HP)[m];                                               \
      h2 p0 = {q[0], q[1]}, p1 = {q[2], q[3]};                      \
      h2 p2 = {q[4], q[5]}, p3 = {q[6], q[7]};                      \
      a0 = dot2(p0, (W)[4 * m + 0], a0);                            \
      a1 = dot2(p1, (W)[4 * m + 1], a1);                            \
      a2 = dot2(p2, (W)[4 * m + 2], a2);                            \
      a3 = dot2(p3, (W)[4 * m + 3], a3);                            \
    }                                                               \
  } while (0)

// One RNN time step (3 layers). Same-wave DS ops are in-order: the b16 write
// of new h is visible to the immediately following uniform reads.
#define STEP(XH)                                                    \
  do {                                                              \
    const h8* hp0 = (const h8*)&hb16[0][0];                         \
    const h8* hp1 = (const h8*)&hb16[1][0];                         \
    const h8* hp2 = (const h8*)&hb16[2][0];                         \
    /* ---- layer 0 ---- */                                         \
    float a0 = bias0, a1 = 0.f, a2 = 0.f, a3 = 0.f;                 \
    a0 = dot2(XH[0], w0i[0], a0); a1 = dot2(XH[1], w0i[1], a1);     \
    a2 = dot2(XH[2], w0i[2], a2); a3 = dot2(XH[3], w0i[3], a3);     \
    a0 = dot2(XH[4], w0i[4], a0); a1 = dot2(XH[5], w0i[5], a1);     \
    a2 = dot2(XH[6], w0i[6], a2); a3 = dot2(XH[7], w0i[7], a3);     \
    HD(hp0, w0h); /* old h0 */                                      \
    const float nh0 = fast_tanh((a0 + a1) + (a2 + a3));             \
    hb16[0][j] = (half_t)nh0;                                       \
    /* ---- layer 1 ---- */                                         \
    a0 = bias1; a1 = a2 = a3 = 0.f;                                 \
    HD(hp0, w1i); /* NEW h0 */                                      \
    HD(hp1, w1h); /* old h1 */                                      \
    const float nh1 = fast_tanh((a0 + a1) + (a2 + a3));             \
    hb16[1][j] = (half_t)nh1;                                       \
    /* ---- layer 2 ---- */                                         \
    a0 = bias2; a1 = a2 = a3 = 0.f;                                 \
    HD(hp1, w2i); /* NEW h1 */                                      \
    HD(hp2, w2h); /* old h2 */                                      \
    nh2v = fast_tanh((a0 + a1) + (a2 + a3));                        \
    hb16[2][j] = (half_t)nh2v;                                      \
  } while (0)

__device__ __forceinline__ void loadx(h2* xh, const float* __restrict__ p) {
  float4 f0 = ((const float4*)p)[0];
  float4 f1 = ((const float4*)p)[1];
  float4 f2 = ((const float4*)p)[2];
  float4 f3 = ((const float4*)p)[3];
  xh[0] = pack2(f0.x, f0.y); xh[1] = pack2(f0.z, f0.w);
  xh[2] = pack2(f1.x, f1.y); xh[3] = pack2(f1.z, f1.w);
  xh[4] = pack2(f2.x, f2.y); xh[5] = pack2(f2.z, f2.w);
  xh[6] = pack2(f3.x, f3.y); xh[7] = pack2(f3.z, f3.w);
}

__global__ __launch_bounds__(64)
__attribute__((amdgpu_waves_per_eu(1, 1)))  // unlock full 512-reg budget (r2: allocator capped at 128)
void rnn3_fused(const float* __restrict__ x,
                const float* __restrict__ wih0, const float* __restrict__ whh0,
                const float* __restrict__ bih0, const float* __restrict__ bhh0,
                const float* __restrict__ wih1, const float* __restrict__ whh1,
                const float* __restrict__ bih1, const float* __restrict__ bhh1,
                const float* __restrict__ wih2, const float* __restrict__ whh2,
                const float* __restrict__ bih2, const float* __restrict__ bhh2,
                const float* __restrict__ fcw, const float* __restrict__ fcb,
                float* __restrict__ out) {
  const int b = blockIdx.x;
  const int j = threadIdx.x;               // lane = hidden unit (j < 40 real)
  const int jr = (j < H_) ? j : (H_ - 1);  // lanes 40..63 duplicate unit 39

  // ---- weights packed fp16: 108 resident VGPRs/lane ----
  h2 w0i[I_ / 2], w0h[H_ / 2], w1i[H_ / 2], w1h[H_ / 2], w2i[H_ / 2], w2h[H_ / 2];
  LOADW(w0i, wih0, I_, I_ / 2)
  LOADW(w0h, whh0, H_, H_ / 2)
  LOADW(w1i, wih1, H_, H_ / 2)
  LOADW(w1h, whh1, H_, H_ / 2)
  LOADW(w2i, wih2, H_, H_ / 2)
  LOADW(w2h, whh2, H_, H_ / 2)

  float bias0 = bih0[jr] + bhh0[jr]; PIN(bias0);
  float bias1 = bih1[jr] + bhh1[jr]; PIN(bias1);
  float bias2 = bih2[jr] + bhh2[jr]; PIN(bias2);

  // h broadcast in fp16: uniform 16B reads = 5 reads per 40-dot, conflict-free.
  __shared__ __align__(16) half_t hb16[3][64];
  hb16[0][j] = (half_t)0.f; hb16[1][j] = (half_t)0.f; hb16[2][j] = (half_t)0.f;
  __syncthreads();

  const float* __restrict__ xb = x + (size_t)b * (T_ * I_);

  // x wave-uniform; packed fp16; 2-buffer / distance-2 prefetch, unroll x2 (no rotate movs)
  h2 xA[8], xB[8];
  loadx(xA, xb);
  loadx(xB, xb + I_);

  float nh2v = 0.f;

  for (int t = 0; t < T_; t += 2) {
    STEP(xA);
    { const int tf = (t + 2 < T_) ? t + 2 : t;     loadx(xA, xb + (size_t)tf * I_); }
    STEP(xB);
    { const int tf = (t + 3 < T_) ? t + 3 : t + 1; loadx(xB, xb + (size_t)tf * I_); }
  }

  // ---- FC head: out[b] = sum_j fc_w[j]*h2[j] + fc_b ----
  const float fw = (j < H_) ? fcw[j] : 0.f;  // dup lanes (40..63) contribute 0
  float v = nh2v * fw;
#pragma unroll
  for (int off = 32; off > 0; off >>= 1) v += __shfl_down(v, off);
  if (j == 0) out[b] = v + fcb[0];
}

extern "C" void kernel_launch(void* const* d_in, const int* in_sizes, int n_in,
                              void* d_out, int out_size, void* d_ws, size_t ws_size,
                              hipStream_t stream) {
  (void)in_sizes; (void)n_in; (void)d_ws; (void)ws_size; (void)out_size;
  const float* x    = (const float*)d_in[0];
  const float* wih0 = (const float*)d_in[1];
  const float* whh0 = (const float*)d_in[2];
  const float* bih0 = (const float*)d_in[3];
  const float* bhh0 = (const float*)d_in[4];
  const float* wih1 = (const float*)d_in[5];
  const float* whh1 = (const float*)d_in[6];
  const float* bih1 = (const float*)d_in[7];
  const float* bhh1 = (const float*)d_in[8];
  const float* wih2 = (const float*)d_in[9];
  const float* whh2 = (const float*)d_in[10];
  const float* bih2 = (const float*)d_in[11];
  const float* bhh2 = (const float*)d_in[12];
  const float* fcw  = (const float*)d_in[13];
  const float* fcb  = (const float*)d_in[14];
  float* out = (float*)d_out;

  hipLaunchKernelGGL(rnn3_fused, dim3(B_), dim3(64), 0, stream,
                     x, wih0, whh0, bih0, bhh0,
                     wih1, whh1, bih1, bhh1,
                     wih2, whh2, bih2, bhh2,
                     fcw, fcb, out);
}